// Round 1
// baseline (509.253 us; speedup 1.0000x reference)
//
#include <hip/hip_runtime.h>

// Outputs (concatenated, each [B, D] float32):
//   0: to_feats        = mean_k features[neigh_idx[b,k]]
//   1: shuf_to_feats   = mean_k features[perm[neigh_idx[b,k]]]
//   2: skip_feats      = features[nodes[b]]
//   3: shuf_skip_feats = features[perm[nodes[b]]]

template <int K, int D>
__global__ __launch_bounds__(256) void mean_agg_kernel(
    const float* __restrict__ features,
    const int* __restrict__ nodes,
    const int* __restrict__ neigh_idx,
    const int* __restrict__ perm,
    float* __restrict__ out,
    int B) {
  // 32 lanes per row, float4 per lane covers D=128 floats.
  const int row = (blockIdx.x << 3) + (threadIdx.x >> 5);
  if (row >= B) return;
  const int d = (threadIdx.x & 31) << 2;  // float index within row

  float4 acc  = make_float4(0.f, 0.f, 0.f, 0.f);
  float4 sacc = make_float4(0.f, 0.f, 0.f, 0.f);

  const int nb = row * K;
#pragma unroll
  for (int k = 0; k < K; ++k) {
    const int idx  = neigh_idx[nb + k];
    const int pidx = perm[idx];
    const float4 f  = *reinterpret_cast<const float4*>(features + (size_t)idx  * D + d);
    const float4 sf = *reinterpret_cast<const float4*>(features + (size_t)pidx * D + d);
    acc.x  += f.x;  acc.y  += f.y;  acc.z  += f.z;  acc.w  += f.w;
    sacc.x += sf.x; sacc.y += sf.y; sacc.z += sf.z; sacc.w += sf.w;
  }

  const float inv = 1.0f / (float)K;
  acc.x  *= inv; acc.y  *= inv; acc.z  *= inv; acc.w  *= inv;
  sacc.x *= inv; sacc.y *= inv; sacc.z *= inv; sacc.w *= inv;

  const int node  = nodes[row];
  const int pnode = perm[node];
  const float4 skip  = *reinterpret_cast<const float4*>(features + (size_t)node  * D + d);
  const float4 sskip = *reinterpret_cast<const float4*>(features + (size_t)pnode * D + d);

  const size_t bd   = (size_t)B * D;
  const size_t base = (size_t)row * D + d;
  *reinterpret_cast<float4*>(out + 0 * bd + base) = acc;
  *reinterpret_cast<float4*>(out + 1 * bd + base) = sacc;
  *reinterpret_cast<float4*>(out + 2 * bd + base) = skip;
  *reinterpret_cast<float4*>(out + 3 * bd + base) = sskip;
}

extern "C" void kernel_launch(void* const* d_in, const int* in_sizes, int n_in,
                              void* d_out, int out_size, void* d_ws, size_t ws_size,
                              hipStream_t stream) {
  const float* features  = (const float*)d_in[0];
  const int*   nodes     = (const int*)d_in[1];
  const int*   neigh_idx = (const int*)d_in[2];
  const int*   perm      = (const int*)d_in[3];
  float*       out       = (float*)d_out;

  const int B = in_sizes[1];  // 100000
  // K = in_sizes[2] / B == 10, D = in_sizes[0] / in_sizes[3] == 128 (compile-time specialized)

  const int rowsPerBlock = 8;  // 256 threads / 32 lanes-per-row
  const int grid = (B + rowsPerBlock - 1) / rowsPerBlock;
  mean_agg_kernel<10, 128><<<grid, 256, 0, stream>>>(
      features, nodes, neigh_idx, perm, out, B);
}